// Round 5
// baseline (909.995 us; speedup 1.0000x reference)
//
#include <hip/hip_runtime.h>
#include <hip/hip_cooperative_groups.h>
#include <stdint.h>

namespace cg = cooperative_groups;

#define TT   500
#define BB   64
#define IND  256
#define HD   512
#define ROWS (TT*BB)   // 32000

typedef __attribute__((ext_vector_type(8))) short sh8;   // 8 bf16
typedef __attribute__((ext_vector_type(4))) float f32x4;

#define SCALE_F ((float)((1.0 - 0.001) / 31.0))

struct P {
  const float *x, *Wch, *W1, *W2, *W3, *W4, *cbetas, *b1, *b2, *b3, *b4;
  uint16_t *wk1, *wk2, *wk3, *wk4, *chs, *sbuf, *mbuf;
  int *n_ch, *n1, *n2, *n3;
  float *spk1, *spk2, *spk3, *spk4, *mem4;
};

__device__ __forceinline__ void load16_lds(const uint16_t* g, uint16_t* l) {
  __builtin_amdgcn_global_load_lds((const __attribute__((address_space(1))) void*)g,
                                   (__attribute__((address_space(3))) void*)l, 16, 0, 0);
}

// ---------------- prep: one element of quantized-weight build (exact np math)
__device__ __forceinline__ void prep_one(int id,
                                         const float* W1, const float* W2,
                                         const float* W3, const float* W4,
                                         uint16_t* wk1, uint16_t* wk2,
                                         uint16_t* wk3, uint16_t* wk4) {
  const float* W; uint16_t* wk; int idx, K, H;
  if (id < 131072)       { idx = id;          W = W1; wk = wk1; K = 256; H = 512; }
  else if (id < 393216)  { idx = id - 131072; W = W2; wk = wk2; K = 512; H = 512; }
  else if (id < 655360)  { idx = id - 393216; W = W3; wk = wk3; K = 512; H = 512; }
  else                   { idx = id - 655360; W = W4; wk = wk4; K = 512; H = 35;  }
  int h = idx / K;
  int k = idx - h * K;
  uint16_t bits = 0;
  if (h < H) {
    float w  = W[h * K + k];
    float wc = fminf(1.0f, fmaxf(0.001f, w));
    float v  = (wc - 0.001f) / SCALE_F;
    float q  = rintf(v);                            // round-half-even = np.round
    bits = (uint16_t)(__float_as_uint(q) >> 16);    // small ints exact in bf16
  }
  wk[idx] = bits;
}

// ---------------- cochlea chain body (xs pre-staged in LDS)
__device__ __forceinline__ void cochlea_body(const float* xs, int b, int i, bool lane0,
                                             const float* Wch, const float* cbetas,
                                             uint16_t* chs, int* n_ch) {
  float w    = Wch[i];
  float beta = fminf(1.0f, fmaxf(0.0f, cbetas[i]));
  float mem  = 0.0f;
  for (int tt = 0; tt < TT; ++tt) {
    float cur = __fmul_rn(xs[tt], w);
    int   rs  = (mem > 1.0f);
    float t2  = __fadd_rn(__fmul_rn(beta, mem), cur);
    mem = rs ? __fsub_rn(t2, 1.0f) : t2;
    int spk = (mem > 1.0f);
    int row = tt * BB + b;
    chs[(size_t)row * IND + i] = spk ? 0x3F80 : 0;
    unsigned long long bal = __ballot(spk);
    if (lane0) atomicAdd(n_ch + row, (int)__popcll(bal));
  }
}

// ---------------- 8-wave 128x128 GEMM tile (exact integer bf16 MFMA)
// tid in [0,512); each wave owns a 64x32 subtile (acc[4][2]).
// LDS: As/Bs 16 KB each, row stride 128 B, XOR slot swizzle (chunk ^ row&7).
template<int K>
__device__ __forceinline__ void gemm_tile8(const uint16_t* __restrict__ A,
                                           const uint16_t* __restrict__ B,
                                           uint16_t* __restrict__ M,
                                           int Hp, int rt, int ct, int tid,
                                           uint16_t* As, uint16_t* Bs) {
  int lane = tid & 63, w = tid >> 6;           // 8 waves
  int r0 = rt * 128, c0 = ct * 128;
  int wr = (w >> 2) * 64, wc = (w & 3) * 32;
  int lr = lane & 15, kgf = lane >> 4;
  f32x4 acc[4][2];
#pragma unroll
  for (int i = 0; i < 4; ++i)
#pragma unroll
    for (int j = 0; j < 2; ++j) acc[i][j] = (f32x4){0, 0, 0, 0};

  for (int k0 = 0; k0 < K; k0 += 64) {
    __syncthreads();   // prior ds_reads done before overwrite
#pragma unroll
    for (int i = 0; i < 2; ++i) {
      int L = i * 512 + tid;          // chunk id 0..1023; wave covers 64 consecutive
      int row = L >> 3, c = L & 7;
      int kg = c ^ (row & 7);
      load16_lds(A + (size_t)(r0 + row) * K + k0 + kg * 8, &As[(i * 512 + w * 64) * 8]);
    }
#pragma unroll
    for (int i = 0; i < 2; ++i) {
      int L = i * 512 + tid;
      int row = L >> 3, c = L & 7;
      int kg = c ^ (row & 7);
      load16_lds(B + (size_t)(c0 + row) * K + k0 + kg * 8, &Bs[(i * 512 + w * 64) * 8]);
    }
    __syncthreads();   // staged data visible
#pragma unroll
    for (int kk = 0; kk < 2; ++kk) {
      sh8 a[4], b[2];
#pragma unroll
      for (int s = 0; s < 4; ++s) {
        int arow = wr + s * 16 + lr;
        int sa   = (kk * 4 + kgf) ^ (arow & 7);
        a[s] = *(const sh8*)&As[arow * 64 + sa * 8];
      }
#pragma unroll
      for (int j = 0; j < 2; ++j) {
        int brow = wc + j * 16 + lr;
        int sb   = (kk * 4 + kgf) ^ (brow & 7);
        b[j] = *(const sh8*)&Bs[brow * 64 + sb * 8];
      }
#pragma unroll
      for (int ar = 0; ar < 4; ++ar)
#pragma unroll
        for (int cs = 0; cs < 2; ++cs)
          acc[ar][cs] = __builtin_amdgcn_mfma_f32_16x16x32_bf16(a[ar], b[cs], acc[ar][cs], 0, 0, 0);
    }
  }
  int oc = lane & 15;
  int rb = (lane >> 4) * 4;
#pragma unroll
  for (int ar = 0; ar < 4; ++ar)
#pragma unroll
    for (int i = 0; i < 4; ++i) {
      size_t rowoff = (size_t)(r0 + wr + ar * 16 + rb + i) * Hp;
#pragma unroll
      for (int cs = 0; cs < 2; ++cs)
        M[rowoff + c0 + wc + cs * 16 + oc] = (uint16_t)acc[ar][cs][i];
    }
}

// ---------------- naive 64x64-per-wave GEMM (layer 4, tiny)
template<int K>
__device__ __forceinline__ void gemm64_naive(const uint16_t* __restrict__ A,
                                             const uint16_t* __restrict__ B,
                                             uint16_t* __restrict__ M,
                                             int Hp, int r0, int c0, int lane) {
  int lr = lane & 15;
  int lk = (lane >> 4) * 8;
  const uint16_t* ap = A + (size_t)(r0 + lr) * K + lk;
  const uint16_t* bp = B + (size_t)(c0 + lr) * K + lk;
  f32x4 acc[4][4];
#pragma unroll
  for (int i = 0; i < 4; ++i)
#pragma unroll
    for (int j = 0; j < 4; ++j) acc[i][j] = (f32x4){0, 0, 0, 0};
#pragma unroll 2
  for (int k = 0; k < K / 32; ++k) {
    sh8 a[4], b[4];
#pragma unroll
    for (int s = 0; s < 4; ++s) {
      a[s] = *(const sh8*)(ap + (size_t)s * 16 * K + k * 32);
      b[s] = *(const sh8*)(bp + (size_t)s * 16 * K + k * 32);
    }
#pragma unroll
    for (int ar = 0; ar < 4; ++ar)
#pragma unroll
      for (int cs = 0; cs < 4; ++cs)
        acc[ar][cs] = __builtin_amdgcn_mfma_f32_16x16x32_bf16(a[ar], b[cs], acc[ar][cs], 0, 0, 0);
  }
  int oc = lane & 15;
  int rb = (lane >> 4) * 4;
#pragma unroll
  for (int ar = 0; ar < 4; ++ar)
#pragma unroll
    for (int i = 0; i < 4; ++i) {
      size_t rowoff = (size_t)(r0 + ar * 16 + rb + i) * Hp;
#pragma unroll
      for (int cs = 0; cs < 4; ++cs)
        M[rowoff + c0 + cs * 16 + oc] = (uint16_t)acc[ar][cs][i];
    }
}

// ---------------- LIF scan bodies (np-exact fp32 recurrence)
__device__ __forceinline__ void scan512_body(int c, bool lane0,
                                             const uint16_t* __restrict__ M,
                                             const int* __restrict__ nrow,
                                             const float* __restrict__ pbeta,
                                             float* __restrict__ spk_out,
                                             uint16_t* __restrict__ s_out,
                                             int* __restrict__ n_out) {
  int b = c >> 9;
  int h = c & 511;
  float beta = fminf(1.0f, fmaxf(0.0f, *pbeta));
  const double DSCALE = (double)SCALE_F;
  const double DWMIN  = (double)0.001f;
  float mem = 0.0f;
  for (int t0 = 0; t0 < TT; t0 += 10) {
    uint16_t mv[10]; int nv[10];
#pragma unroll
    for (int j = 0; j < 10; ++j) {
      int row = (t0 + j) * BB + b;
      mv[j] = M[(size_t)row * HD + h];
      nv[j] = nrow[row];
    }
#pragma unroll
    for (int j = 0; j < 10; ++j) {
      int tt = t0 + j;
      int row = tt * BB + b;
      float cur = (float)((double)mv[j] * DSCALE + (double)nv[j] * DWMIN);
      int   rs  = (mem > 1.0f);
      float t2  = __fadd_rn(__fmul_rn(beta, mem), cur);
      mem = rs ? __fsub_rn(t2, 1.0f) : t2;
      int spk = (mem > 1.0f);
      spk_out[(size_t)tt * (BB * HD) + c] = spk ? 1.0f : 0.0f;
      s_out[(size_t)row * HD + h] = spk ? 0x3F80 : 0;
      unsigned long long bal = __ballot(spk);
      if (lane0) atomicAdd(n_out + row, (int)__popcll(bal));
    }
  }
}

__device__ __forceinline__ void scanl4_body(int c,
                                            const uint16_t* __restrict__ M,
                                            const int* __restrict__ nrow,
                                            const float* __restrict__ pbeta,
                                            float* __restrict__ spk_out,
                                            float* __restrict__ mem_out) {
  int b = c / 35;
  int h = c - b * 35;
  float beta = fminf(1.0f, fmaxf(0.0f, *pbeta));
  const double DSCALE = (double)SCALE_F;
  const double DWMIN  = (double)0.001f;
  float mem = 0.0f;
  for (int t0 = 0; t0 < TT; t0 += 10) {
    uint16_t mv[10]; int nv[10];
#pragma unroll
    for (int j = 0; j < 10; ++j) {
      int row = (t0 + j) * BB + b;
      mv[j] = M[(size_t)row * 64 + h];
      nv[j] = nrow[row];
    }
#pragma unroll
    for (int j = 0; j < 10; ++j) {
      int tt = t0 + j;
      float cur = (float)((double)mv[j] * DSCALE + (double)nv[j] * DWMIN);
      int   rs  = (mem > 1.0f);
      float t2  = __fadd_rn(__fmul_rn(beta, mem), cur);
      mem = rs ? __fsub_rn(t2, 1.0f) : t2;
      int spk = (mem > 1.0f);
      spk_out[(size_t)tt * (BB * 35) + c] = spk ? 1.0f : 0.0f;
      mem_out[(size_t)tt * (BB * 35) + c] = mem;
    }
  }
}

// ================= fused cooperative kernel: 256 blocks x 512 threads =========
__global__ __launch_bounds__(512) void k_mega(P p) {
  cg::grid_group grid = cg::this_grid();
  __shared__ uint16_t As[8192];   // 16 KB
  __shared__ uint16_t Bs[8192];   // 16 KB
  int g = blockIdx.x, t = threadIdx.x;

  // P0: build quantized weights (n-counters pre-zeroed by host memsetAsync)
  for (int i = g * 512 + t; i < 688128; i += 131072)
    prep_one(i, p.W1, p.W2, p.W3, p.W4, p.wk1, p.wk2, p.wk3, p.wk4);
  grid.sync();

  // P1: cochlea — 4 blocks per batch, 64 channels each
  {
    float* xs = (float*)As;
    int b = g >> 2;
    for (int tt = t; tt < TT; tt += 512) xs[tt] = p.x[b * TT + tt];
    __syncthreads();
    if (t < 64) cochlea_body(xs, b, (g & 3) * 64 + t, t == 0, p.Wch, p.cbetas, p.chs, p.n_ch);
  }
  grid.sync();

  // L1
  for (int tile = g; tile < 1000; tile += 256)
    gemm_tile8<256>(p.chs, p.wk1, p.mbuf, HD, tile >> 2, tile & 3, t, As, Bs);
  grid.sync();
  if (t < 128) scan512_body(g * 128 + t, (t & 63) == 0, p.mbuf, p.n_ch, p.b1, p.spk1, p.sbuf, p.n1);
  grid.sync();
  // L2
  for (int tile = g; tile < 1000; tile += 256)
    gemm_tile8<512>(p.sbuf, p.wk2, p.mbuf, HD, tile >> 2, tile & 3, t, As, Bs);
  grid.sync();
  if (t < 128) scan512_body(g * 128 + t, (t & 63) == 0, p.mbuf, p.n1, p.b2, p.spk2, p.sbuf, p.n2);
  grid.sync();
  // L3
  for (int tile = g; tile < 1000; tile += 256)
    gemm_tile8<512>(p.sbuf, p.wk3, p.mbuf, HD, tile >> 2, tile & 3, t, As, Bs);
  grid.sync();
  if (t < 128) scan512_body(g * 128 + t, (t & 63) == 0, p.mbuf, p.n2, p.b3, p.spk3, p.sbuf, p.n3);
  grid.sync();
  // L4 GEMM: 500 64-row tiles, one wave each
  {
    int wid = g * 8 + (t >> 6);
    if (wid < 500) gemm64_naive<512>(p.sbuf, p.wk4, p.mbuf, 64, wid * 64, 0, t & 63);
  }
  grid.sync();
  if (t < 128) {
    int c = g * 128 + t;
    if (c < BB * 35) scanl4_body(c, p.mbuf, p.n3, p.b4, p.spk4, p.mem4);
  }
}

// ================= standalone fallback kernels (proven R3 path) ===============
__global__ __launch_bounds__(256) void k_prep_sa(const float* W1, const float* W2,
                                                 const float* W3, const float* W4,
                                                 uint16_t* wk1, uint16_t* wk2,
                                                 uint16_t* wk3, uint16_t* wk4) {
  prep_one(blockIdx.x * 256 + threadIdx.x, W1, W2, W3, W4, wk1, wk2, wk3, wk4);
}

__global__ __launch_bounds__(64) void k_cochlea_sa(const float* x, const float* Wch,
                                                   const float* cbetas,
                                                   uint16_t* chs, int* n_ch) {
  __shared__ float xs[TT];
  int b = blockIdx.x >> 2;
  for (int tt = threadIdx.x; tt < TT; tt += 64) xs[tt] = x[b * TT + tt];
  __syncthreads();
  cochlea_body(xs, b, (blockIdx.x & 3) * 64 + threadIdx.x, threadIdx.x == 0,
               Wch, cbetas, chs, n_ch);
}

template<int K>
__global__ __launch_bounds__(512) void k_gemm8_sa(const uint16_t* A, const uint16_t* B,
                                                  uint16_t* M, int Hp, int coltiles) {
  __shared__ uint16_t As[8192];
  __shared__ uint16_t Bs[8192];
  gemm_tile8<K>(A, B, M, Hp, blockIdx.x / coltiles, blockIdx.x % coltiles,
                threadIdx.x, As, Bs);
}

__global__ __launch_bounds__(128) void k_scan512_sa(const uint16_t* M, const int* nrow,
                                                    const float* pbeta, float* spk_out,
                                                    uint16_t* s_out, int* n_out) {
  scan512_body(blockIdx.x * 128 + threadIdx.x, (threadIdx.x & 63) == 0,
               M, nrow, pbeta, spk_out, s_out, n_out);
}

template<int K>
__global__ __launch_bounds__(256) void k_gemm_naive_sa(const uint16_t* A, const uint16_t* B,
                                                       uint16_t* M, int Hp) {
  int wid = (blockIdx.x * 256 + threadIdx.x) >> 6;
  if (wid < 500) gemm64_naive<K>(A, B, M, Hp, wid * 64, 0, threadIdx.x & 63);
}

__global__ __launch_bounds__(128) void k_scanl4_sa(const uint16_t* M, const int* nrow,
                                                   const float* pbeta, float* spk_out,
                                                   float* mem_out) {
  int c = blockIdx.x * 128 + threadIdx.x;
  if (c < BB * 35) scanl4_body(c, M, nrow, pbeta, spk_out, mem_out);
}

// ---------------- launch
extern "C" void kernel_launch(void* const* d_in, const int* in_sizes, int n_in,
                              void* d_out, int out_size, void* d_ws, size_t ws_size,
                              hipStream_t stream) {
  uint8_t* ws = (uint8_t*)d_ws;
  P p;
  p.x      = (const float*)d_in[0];
  p.Wch    = (const float*)d_in[1];
  p.W1     = (const float*)d_in[2];
  p.W2     = (const float*)d_in[3];
  p.W3     = (const float*)d_in[4];
  p.W4     = (const float*)d_in[5];
  p.cbetas = (const float*)d_in[6];
  p.b1     = (const float*)d_in[7];
  p.b2     = (const float*)d_in[8];
  p.b3     = (const float*)d_in[9];
  p.b4     = (const float*)d_in[10];

  p.wk1  = (uint16_t*)(ws + 0);         // 512*256*2
  p.wk2  = (uint16_t*)(ws + 262144);    // 512*512*2
  p.wk3  = (uint16_t*)(ws + 786432);
  p.wk4  = (uint16_t*)(ws + 1310720);   // 64*512*2
  p.n_ch = (int*)(ws + 1376256);        // 4 x 32000 ints contiguous
  p.n1   = (int*)(ws + 1504256);
  p.n2   = (int*)(ws + 1632256);
  p.n3   = (int*)(ws + 1760256);
  p.chs  = (uint16_t*)(ws + 1888256);   // 32000*256*2
  p.sbuf = (uint16_t*)(ws + 18272256);  // 32000*512*2
  p.mbuf = (uint16_t*)(ws + 51040256);  // 32000*512*2

  float* out = (float*)d_out;
  p.spk1 = out;
  p.spk2 = out + 16384000;
  p.spk3 = out + 32768000;
  p.spk4 = out + 49152000;
  p.mem4 = out + 50272000;

  // zero the spike-count atomic accumulators (needed by both paths)
  hipMemsetAsync(ws + 1376256, 0, 512000, stream);

  void* args[] = {(void*)&p};
  hipError_t rc = hipLaunchCooperativeKernel((const void*)k_mega, dim3(256), dim3(512),
                                             args, 0, stream);
  if (rc != hipSuccess) {
    (void)hipGetLastError();   // clear sticky error, run proven multi-kernel path
    k_prep_sa<<<2688, 256, 0, stream>>>(p.W1, p.W2, p.W3, p.W4, p.wk1, p.wk2, p.wk3, p.wk4);
    k_cochlea_sa<<<256, 64, 0, stream>>>(p.x, p.Wch, p.cbetas, p.chs, p.n_ch);
    k_gemm8_sa<256><<<1000, 512, 0, stream>>>(p.chs, p.wk1, p.mbuf, HD, 4);
    k_scan512_sa<<<256, 128, 0, stream>>>(p.mbuf, p.n_ch, p.b1, p.spk1, p.sbuf, p.n1);
    k_gemm8_sa<512><<<1000, 512, 0, stream>>>(p.sbuf, p.wk2, p.mbuf, HD, 4);
    k_scan512_sa<<<256, 128, 0, stream>>>(p.mbuf, p.n1, p.b2, p.spk2, p.sbuf, p.n2);
    k_gemm8_sa<512><<<1000, 512, 0, stream>>>(p.sbuf, p.wk3, p.mbuf, HD, 4);
    k_scan512_sa<<<256, 128, 0, stream>>>(p.mbuf, p.n2, p.b3, p.spk3, p.sbuf, p.n3);
    k_gemm_naive_sa<512><<<125, 256, 0, stream>>>(p.sbuf, p.wk4, p.mbuf, 64);
    k_scanl4_sa<<<18, 128, 0, stream>>>(p.mbuf, p.n3, p.b4, p.spk4, p.mem4);
  }
}

// Round 6
// 649.907 us; speedup vs baseline: 1.4002x; 1.4002x over previous
//
#include <hip/hip_runtime.h>
#include <stdint.h>

#define TT   500
#define BB   64
#define IND  256
#define HD   512
#define ROWS (TT*BB)   // 32000

typedef __attribute__((ext_vector_type(8))) short sh8;   // 8 bf16
typedef __attribute__((ext_vector_type(4))) float f32x4;
typedef __attribute__((ext_vector_type(4))) int   i32x4;

#define SCALE_F ((float)((1.0 - 0.001) / 31.0))

__device__ __forceinline__ void load16_lds(const uint16_t* g, uint16_t* l) {
  __builtin_amdgcn_global_load_lds((const __attribute__((address_space(1))) void*)g,
                                   (__attribute__((address_space(3))) void*)l, 16, 0, 0);
}

// ---------------- prep: quantized-weight build (exact np math); wk4 padded to 128 rows
__device__ __forceinline__ void prep_one(int id,
                                         const float* W1, const float* W2,
                                         const float* W3, const float* W4,
                                         uint16_t* wk1, uint16_t* wk2,
                                         uint16_t* wk3, uint16_t* wk4) {
  const float* W; uint16_t* wk; int idx, K, H;
  if (id < 131072)       { idx = id;          W = W1; wk = wk1; K = 256; H = 512; }
  else if (id < 393216)  { idx = id - 131072; W = W2; wk = wk2; K = 512; H = 512; }
  else if (id < 655360)  { idx = id - 393216; W = W3; wk = wk3; K = 512; H = 512; }
  else                   { idx = id - 655360; W = W4; wk = wk4; K = 512; H = 35;  }
  int h = idx / K;
  int k = idx - h * K;
  uint16_t bits = 0;
  if (h < H) {
    float w  = W[h * K + k];
    float wc = fminf(1.0f, fmaxf(0.001f, w));
    float v  = (wc - 0.001f) / SCALE_F;
    float q  = rintf(v);                            // round-half-even = np.round
    bits = (uint16_t)(__float_as_uint(q) >> 16);    // small ints exact in bf16
  }
  wk[idx] = bits;
}

// ---------------- fused prep + cochlea
// blocks 0..2815: prep (720896 elems). blocks 2816..2879: cochlea, b = blk-2816,
// 4 waves, wave w owns channels w*64..w*64+63; writes PACKED spikes + n atomics.
__global__ __launch_bounds__(256) void k_prep_coch(const float* __restrict__ W1,
                                                   const float* __restrict__ W2,
                                                   const float* __restrict__ W3,
                                                   const float* __restrict__ W4,
                                                   uint16_t* __restrict__ wk1,
                                                   uint16_t* __restrict__ wk2,
                                                   uint16_t* __restrict__ wk3,
                                                   uint16_t* __restrict__ wk4,
                                                   const float* __restrict__ x,
                                                   const float* __restrict__ Wch,
                                                   const float* __restrict__ cbetas,
                                                   uint64_t* __restrict__ chp,
                                                   int* __restrict__ n_ch) {
  __shared__ float xs[TT];
  int g = blockIdx.x, t = threadIdx.x;
  if (g < 2816) {
    int id = g * 256 + t;
    if (id < 720896) prep_one(id, W1, W2, W3, W4, wk1, wk2, wk3, wk4);
    return;
  }
  int b = g - 2816;
  for (int tt = t; tt < TT; tt += 256) xs[tt] = x[b * TT + tt];
  __syncthreads();
  int wv = t >> 6, lane = t & 63;
  float w    = Wch[t];
  float beta = fminf(1.0f, fmaxf(0.0f, cbetas[t]));
  float mem  = 0.0f;
  for (int tt = 0; tt < TT; ++tt) {
    float cur = __fmul_rn(xs[tt], w);
    int   rs  = (mem > 1.0f);
    float t2  = __fadd_rn(__fmul_rn(beta, mem), cur);
    mem = rs ? __fsub_rn(t2, 1.0f) : t2;
    int spk = (mem > 1.0f);
    int row = tt * BB + b;
    unsigned long long bal = __ballot(spk);
    if (lane == 0) {
      chp[(size_t)row * 4 + wv] = bal;
      atomicAdd(n_ch + row, (int)__popcll(bal));
    }
  }
}

// ---------------- packed-A LDS MFMA GEMM: 128x128 tile, 4 waves (64x64 each)
// A: packed spikes (1 bit), row stride K/64 u64 words; staged once per tile into
// padded LDS (80 B rows). B: bf16 [rows][K], staged per-k0 via global_load_lds
// with XOR swizzle (R3-proven). Exact integer bf16 MFMA, f32 accum.
template<int K, bool HALF>
__global__ __launch_bounds__(256) void k_gemm_p(const uint64_t* __restrict__ Apk,
                                                const uint16_t* __restrict__ B,
                                                uint16_t* __restrict__ M,
                                                int Hp, int coltiles) {
  __shared__ uint16_t Bs[8192];      // 16 KB
  __shared__ uint8_t  Ap[128 * 80];  // 10 KB, padded row stride 80 B
  int tid = threadIdx.x;
  int lane = tid & 63, w = tid >> 6;
  int rt = blockIdx.x / coltiles, ct = blockIdx.x - rt * coltiles;
  int r0 = rt * 128, c0 = ct * 128;
  int wr = (w >> 1) * 64, wc = (w & 1) * 64;
  int lr = lane & 15, kgf = lane >> 4;

  // stage packed A tile (contiguous global region, 4/8 KB)
  {
    const uint8_t* src = (const uint8_t*)(Apk + (size_t)r0 * (K / 64));
    constexpr int CPR = (K / 8) / 16;          // 16B chunks per row: 2 or 4
    constexpr int CH  = 128 * CPR;             // 256 or 512
#pragma unroll
    for (int chunk = tid; chunk < CH; chunk += 256) {
      i32x4 v = *(const i32x4*)(src + (size_t)chunk * 16);
      int r = chunk / CPR, off = (chunk - r * CPR) * 16;
      *(i32x4*)&Ap[r * 80 + off] = v;
    }
  }

  f32x4 acc[4][4];
#pragma unroll
  for (int i = 0; i < 4; ++i)
#pragma unroll
    for (int j = 0; j < 4; ++j) acc[i][j] = (f32x4){0, 0, 0, 0};

  for (int k0 = 0; k0 < K; k0 += 64) {
    __syncthreads();   // prior reads done; also orders A-stage before first use
#pragma unroll
    for (int i = 0; i < 4; ++i) {
      int L = i * 256 + tid;
      int row = L >> 3, c = L & 7;
      int kg = c ^ (row & 7);
      load16_lds(B + (size_t)(c0 + row) * K + k0 + kg * 8, &Bs[(i * 256 + w * 64) * 8]);
    }
    __syncthreads();   // staged B visible
    uint64_t wA[4];
#pragma unroll
    for (int s = 0; s < 4; ++s) {
      int arow = wr + s * 16 + lr;
      wA[s] = *(const uint64_t*)&Ap[arow * 80 + (k0 >> 3)];
    }
#pragma unroll
    for (int kk = 0; kk < 2; ++kk) {
      sh8 a[4], b[4];
#pragma unroll
      for (int s = 0; s < 4; ++s) {
        uint32_t byte = (uint32_t)(wA[s] >> (kk * 32 + kgf * 8)) & 0xFFu;
#pragma unroll
        for (int j = 0; j < 8; ++j)
          a[s][j] = ((byte >> j) & 1) ? (short)0x3F80 : (short)0;
      }
#pragma unroll
      for (int s = 0; s < 4; ++s) {
        int brow = wc + s * 16 + lr;
        int sb   = (kk * 4 + kgf) ^ (brow & 7);
        b[s] = *(const sh8*)&Bs[brow * 64 + sb * 8];
      }
#pragma unroll
      for (int ar = 0; ar < 4; ++ar)
#pragma unroll
        for (int cs = 0; cs < 4; ++cs)
          acc[ar][cs] = __builtin_amdgcn_mfma_f32_16x16x32_bf16(a[ar], b[cs], acc[ar][cs], 0, 0, 0);
    }
  }
  // C/D layout: col = lane&15, row = (lane>>4)*4 + reg
  int oc = lane & 15;
  int rb = (lane >> 4) * 4;
#pragma unroll
  for (int ar = 0; ar < 4; ++ar)
#pragma unroll
    for (int i = 0; i < 4; ++i) {
      size_t rowoff = (size_t)(r0 + wr + ar * 16 + rb + i) * Hp;
#pragma unroll
      for (int cs = 0; cs < 4; ++cs) {
        int col = wc + cs * 16 + oc;
        if (!HALF || col < 64) M[rowoff + c0 + col] = (uint16_t)acc[ar][cs][i];
      }
    }
}

// ---------------- LIF scan, H=512 (np-exact fp32 recurrence), prefetch-pipelined
__global__ __launch_bounds__(64) void k_scan512(const uint16_t* __restrict__ M,
                                                const int* __restrict__ nrow,
                                                const float* __restrict__ pbeta,
                                                float* __restrict__ spk_out,
                                                uint64_t* __restrict__ spkp,
                                                int* __restrict__ n_out) {
  int t = threadIdx.x;
  int c = blockIdx.x * 64 + t;
  int b = c >> 9;              // block-uniform
  int h = c & 511;
  int word = h >> 6;           // block-uniform
  float beta = fminf(1.0f, fmaxf(0.0f, *pbeta));
  const double DSCALE = (double)SCALE_F;
  const double DWMIN  = (double)0.001f;
  float mem = 0.0f;
  uint16_t mvA[10], mvB[10]; int nvA[10], nvB[10];
#pragma unroll
  for (int j = 0; j < 10; ++j) {
    int row = j * BB + b;
    mvA[j] = M[(size_t)row * HD + h];
    nvA[j] = nrow[row];
  }
  for (int t0 = 0; t0 < TT; t0 += 10) {
    if (t0 + 10 < TT) {
#pragma unroll
      for (int j = 0; j < 10; ++j) {
        int row = (t0 + 10 + j) * BB + b;
        mvB[j] = M[(size_t)row * HD + h];
        nvB[j] = nrow[row];
      }
    }
#pragma unroll
    for (int j = 0; j < 10; ++j) {
      int tt = t0 + j;
      int row = tt * BB + b;
      float cur = (float)((double)mvA[j] * DSCALE + (double)nvA[j] * DWMIN);
      int   rs  = (mem > 1.0f);
      float t2  = __fadd_rn(__fmul_rn(beta, mem), cur);
      mem = rs ? __fsub_rn(t2, 1.0f) : t2;
      int spk = (mem > 1.0f);
      spk_out[(size_t)tt * (BB * HD) + c] = spk ? 1.0f : 0.0f;
      unsigned long long bal = __ballot(spk);
      if (t == 0) {
        spkp[(size_t)row * 8 + word] = bal;
        atomicAdd(n_out + row, (int)__popcll(bal));
      }
    }
#pragma unroll
    for (int j = 0; j < 10; ++j) { mvA[j] = mvB[j]; nvA[j] = nvB[j]; }
  }
}

// ---------------- LIF scan, layer 4 (H=35, Hp=64, writes spk4 + mem4)
__global__ __launch_bounds__(64) void k_scanl4(const uint16_t* __restrict__ M,
                                               const int* __restrict__ nrow,
                                               const float* __restrict__ pbeta,
                                               float* __restrict__ spk_out,
                                               float* __restrict__ mem_out) {
  int c = blockIdx.x * 64 + threadIdx.x;
  if (c >= BB * 35) return;
  int b = c / 35;
  int h = c - b * 35;
  float beta = fminf(1.0f, fmaxf(0.0f, *pbeta));
  const double DSCALE = (double)SCALE_F;
  const double DWMIN  = (double)0.001f;
  float mem = 0.0f;
  for (int t0 = 0; t0 < TT; t0 += 10) {
    uint16_t mv[10]; int nv[10];
#pragma unroll
    for (int j = 0; j < 10; ++j) {
      int row = (t0 + j) * BB + b;
      mv[j] = M[(size_t)row * 64 + h];
      nv[j] = nrow[row];
    }
#pragma unroll
    for (int j = 0; j < 10; ++j) {
      int tt = t0 + j;
      float cur = (float)((double)mv[j] * DSCALE + (double)nv[j] * DWMIN);
      int   rs  = (mem > 1.0f);
      float t2  = __fadd_rn(__fmul_rn(beta, mem), cur);
      mem = rs ? __fsub_rn(t2, 1.0f) : t2;
      int spk = (mem > 1.0f);
      spk_out[(size_t)tt * (BB * 35) + c] = spk ? 1.0f : 0.0f;
      mem_out[(size_t)tt * (BB * 35) + c] = mem;
    }
  }
}

// ---------------- launch
extern "C" void kernel_launch(void* const* d_in, const int* in_sizes, int n_in,
                              void* d_out, int out_size, void* d_ws, size_t ws_size,
                              hipStream_t stream) {
  const float* x      = (const float*)d_in[0];
  const float* Wch    = (const float*)d_in[1];
  const float* W1     = (const float*)d_in[2];
  const float* W2     = (const float*)d_in[3];
  const float* W3     = (const float*)d_in[4];
  const float* W4     = (const float*)d_in[5];
  const float* cbetas = (const float*)d_in[6];
  const float* b1     = (const float*)d_in[7];
  const float* b2     = (const float*)d_in[8];
  const float* b3     = (const float*)d_in[9];
  const float* b4     = (const float*)d_in[10];

  uint8_t* ws = (uint8_t*)d_ws;
  uint16_t* wk1  = (uint16_t*)(ws + 0);         // 512*256*2 = 262144
  uint16_t* wk2  = (uint16_t*)(ws + 262144);    // 512*512*2 = 524288
  uint16_t* wk3  = (uint16_t*)(ws + 786432);    // 524288
  uint16_t* wk4  = (uint16_t*)(ws + 1310720);   // 128*512*2 = 131072 (padded rows)
  int*      n_ch = (int*)(ws + 1441792);        // 4 x 128000 B contiguous
  int*      n1   = (int*)(ws + 1569792);
  int*      n2   = (int*)(ws + 1697792);
  int*      n3   = (int*)(ws + 1825792);        // ends 1953792
  uint64_t* chp  = (uint64_t*)(ws + 1953792);   // 32000*4 words = 1024000
  uint64_t* sbp  = (uint64_t*)(ws + 2977792);   // 32000*8 words = 2048000
  uint16_t* mbuf = (uint16_t*)(ws + 5025792);   // 32000*512*2 = 32768000

  float* out  = (float*)d_out;
  float* spk1 = out;                // 500*64*512
  float* spk2 = out + 16384000;
  float* spk3 = out + 32768000;
  float* spk4 = out + 49152000;     // 500*64*35
  float* mem4 = out + 50272000;

  // zero spike-count atomic accumulators
  hipMemsetAsync(ws + 1441792, 0, 512000, stream);

  // prep (2816 blocks) + cochlea (64 blocks) fused
  k_prep_coch<<<2880, 256, 0, stream>>>(W1, W2, W3, W4, wk1, wk2, wk3, wk4,
                                        x, Wch, cbetas, chp, n_ch);

  // L1: K=256, 250 rowtiles x 4 coltiles
  k_gemm_p<256, false><<<1000, 256, 0, stream>>>(chp, wk1, mbuf, HD, 4);
  k_scan512<<<512, 64, 0, stream>>>(mbuf, n_ch, b1, spk1, sbp, n1);

  // L2
  k_gemm_p<512, false><<<1000, 256, 0, stream>>>(sbp, wk2, mbuf, HD, 4);
  k_scan512<<<512, 64, 0, stream>>>(mbuf, n1, b2, spk2, sbp, n2);

  // L3
  k_gemm_p<512, false><<<1000, 256, 0, stream>>>(sbp, wk3, mbuf, HD, 4);
  k_scan512<<<512, 64, 0, stream>>>(mbuf, n2, b3, spk3, sbp, n3);

  // L4: 128-wide tile, only cols<64 stored (HALF), 250 rowtiles
  k_gemm_p<512, true><<<250, 256, 0, stream>>>(sbp, wk4, mbuf, 64, 1);
  k_scanl4<<<35, 64, 0, stream>>>(mbuf, n3, b4, spk4, mem4);
}